// Round 12
// baseline (207.174 us; speedup 1.0000x reference)
//
#include <hip/hip_runtime.h>
#include <hip/hip_bf16.h>
#include <stdint.h>

typedef __bf16 bf16_t;
typedef bf16_t bf16x8 __attribute__((ext_vector_type(8)));
typedef float f32x4 __attribute__((ext_vector_type(4)));

#define DEVI static __device__ __forceinline__

constexpr int NB = 32, CIN = 256, COUT = 256, KNUM = 6, ET = 3, TDIM = 64, VV = 25;
constexpr int KD   = KNUM * CIN;       // 1536 contraction dim (k,ci)
constexpr long OUT0 = (long)NB * COUT * TDIM * VV;  // 13107200 (x_sum elems)
constexpr int ACNT = ET * VV * VV;     // 1875 (A copy)

// wp3: W in fragment-order. 24 steps x 2048 chunks x 16B = 768 KB. (R7 layout)
constexpr int NSTEP = 24;              // 4 cb x 6 k
constexpr int WP3_CHUNKS = NSTEP * 2048;
constexpr size_t WP3_BYTES  = (size_t)WP3_CHUNKS * 16;      // 768 KB
constexpr size_t BIAS_OFF   = WP3_BYTES;
constexpr size_t BIAS_BYTES = (size_t)NB * VV * COUT * 4;   // bias [n][w][c] f32
constexpr size_t WS_NEED    = BIAS_OFF + BIAS_BYTES;

DEVI unsigned packbf(float lo, float hi) {
  unsigned short a = __builtin_bit_cast(unsigned short, (bf16_t)lo);
  unsigned short b = __builtin_bit_cast(unsigned short, (bf16_t)hi);
  return ((unsigned)b << 16) | (unsigned)a;
}

DEVI bf16x8 pack8(f32x4 a, f32x4 b) {
  union { unsigned u[4]; bf16x8 v; } u;
  u.u[0] = packbf(a[0], a[1]); u.u[1] = packbf(a[2], a[3]);
  u.u[2] = packbf(b[0], b[1]); u.u[3] = packbf(b[2], b[3]);
  return u.v;
}

// ---------------- prep: wp3 fragment-layout + bias table + A copy ----------
__global__ __launch_bounds__(256) void prep_kernel(
    const float* __restrict__ A, const float* __restrict__ Bm,
    const float* __restrict__ lam_p, const float* __restrict__ W,
    const float* __restrict__ bvec, bf16_t* __restrict__ wp3,
    float* __restrict__ biasmat, float* __restrict__ outA)
{
  int idx = blockIdx.x * 256 + threadIdx.x;
  constexpr int S1 = WP3_CHUNKS;            // 49152 (one 16B chunk per thread)
  constexpr int S2 = S1 + NB * VV * COUT;   // +204800
  constexpr int S3 = S2 + ACNT;
  if (idx < S1) {
    int s  = idx >> 11;
    int r  = idx & 2047;
    int mi = r >> 7;
    int kk = (r >> 6) & 1;
    int ln = r & 63;
    int lg = ln >> 4, lw = ln & 15;
    int cb = s / 6, k = s - cb * 6;
    int cibase = cb * 64 + (lg + 4 * kk) * 8;
    int col = (k << 8) + mi * 16 + lw;
    bf16_t* dst = wp3 + ((long)idx << 3);
    #pragma unroll
    for (int e = 0; e < 8; ++e)
      dst[e] = (bf16_t)W[(cibase + e) * KD + col];
  } else if (idx < S2) {
    // bias[n][w][c] = sum_k b[k*256+c] * S[n,k,w],  S = col-sum of M (lam folded)
    int j = idx - S1;
    int c = j & 255;
    int nw = j >> 8;
    int w = nw % VV;
    int n = nw / VV;
    float lam = lam_p[0];
    float s = 0.f;
    for (int k = 0; k < KNUM; ++k) {
      float sk = 0.f;
      if (k < ET) {
        for (int v = 0; v < VV; ++v) sk += A[(k * VV + v) * VV + w];
      } else {
        for (int v = 0; v < VV; ++v) sk += Bm[(((n * ET) + (k - ET)) * VV + v) * VV + w];
        sk *= lam;
      }
      s += bvec[(k << 8) + c] * sk;
    }
    biasmat[j] = s;
  } else if (idx < S3) {
    int j = idx - S2;
    outA[j] = A[j];   // second tuple output: A passthrough
  }
}

// ---------------- fused kernel: barrier-free k-loop, reg-chained #1 -> #2 ----
// Grid 1024: block = (m-half, n, 4 t's). Wave wv owns col-tile ct=wv (16 cols:
// dt=ct>>1, w range (ct&1)*16..+15) x 8 m-tiles (mh half). Per step (cb,k):
//   #1: 2 MFMA per kk (Xs permuted rows x Ms) -> pack8 -> bfrag[kk] IS the
//       16x16x32 B-fragment (R8-verified construction, zero duplication).
//   #2: 16 MFMA, af2 streamed from wp3 (frag-order, L2-hot).
// k-loop has NO LDS writes and NO barriers; only Xs restage barriers (2/cb).
__global__ __launch_bounds__(512, 4) void fused_kernel(
    const float* __restrict__ x, const float* __restrict__ A,
    const float* __restrict__ Bm, const float* __restrict__ lam_p,
    const bf16_t* __restrict__ wp3, const float* __restrict__ biasmat,
    float* __restrict__ out)
{
  __shared__ __align__(16) bf16_t Xs[256 * 32];      // 16 KB, permuted rows (R8)
  __shared__ __align__(16) bf16_t Ms[KNUM * 32 * 32];// 12 KB, swizzled (R11)

  const int b = blockIdx.x;
  const int mh = b >> 9;                 // m-half (0: c 0..127, 1: c 128..255)
  const int rest = b & 511;
  const int n = rest >> 4;               // 0..31
  const int t0 = (rest & 15) << 2;       // t-group of 4
  const int tid = threadIdx.x;
  const int wv = tid >> 6, ln = tid & 63;
  const int lw = ln & 15, lg = ln >> 4;
  const int dt = wv >> 1, wsel = wv & 1; // wave's col-tile: dt, w-half
  const float lam = lam_p[0];

  // stage Ms once: row R=k*32+w (64B), group-XOR sw2=(w&3)^((w>>2)&3)  [R11]
  for (int i = tid; i < KNUM * 32 * 32; i += 512) {
    int R = i >> 5, v = i & 31;
    int k = i >> 10, w = (i >> 5) & 31;
    float val = 0.f;
    if (w < VV && v < VV)
      val = (k < ET) ? A[(k * VV + v) * VV + w]
                     : lam * Bm[(((n * ET) + (k - ET)) * VV + v) * VV + w];
    int sw2 = (w & 3) ^ ((w >> 2) & 3);
    int byteoff = R * 64 + ((((v >> 3) ^ sw2) & 3) << 4) + ((v & 7) << 1);
    *(bf16_t*)((char*)Ms + byteoff) = (bf16_t)val;
  }

  f32x4 acc[8] = {};
  const f32x4 z4 = {0.f, 0.f, 0.f, 0.f};
  const int msw2 = (lw & 3) ^ ((lw >> 2) & 3);   // Ms read swizzle

  #pragma unroll 1
  for (int cb = 0; cb < 4; ++cb) {
    __syncthreads();   // all waves done reading previous cb's Xs
    // stage Xs, PERMUTED rows (R8-verified): ci -> row' = dt*64 + kk*32
    //   + (r>>2)*16 + q*4 + (r&3)  with kk=ci>>5, q=(ci>>3)&3, r=ci&7
    if (tid < 256) {
      int ci = tid >> 2, dtl = tid & 3;
      const float* xp = x + ((long)(n * CIN + cb * 64 + ci) * TDIM + t0 + dtl) * VV;
      float xv[25];
      #pragma unroll
      for (int v = 0; v < VV; ++v) xv[v] = xp[v];
      int kk2 = ci >> 5, rem = ci & 31, q = rem >> 3, r = rem & 7;
      int row = dtl * 64 + kk2 * 32 + (r >> 2) * 16 + q * 4 + (r & 3);
      int sw = (row & 3) ^ ((row >> 2) & 3);
      #pragma unroll
      for (int g = 0; g < 4; ++g) {
        char* base = (char*)Xs + row * 64 + ((g ^ sw) & 3) * 16;
        #pragma unroll
        for (int p = 0; p < 4; ++p) {
          int v0 = g * 8 + p * 2;
          float lo = (v0     < VV) ? xv[v0 < VV ? v0 : 0]     : 0.f;
          float hi = (v0 + 1 < VV) ? xv[v0 + 1 < VV ? v0 + 1 : 0] : 0.f;
          *(unsigned*)(base + p * 4) = packbf(lo, hi);
        }
      }
    }
    __syncthreads();   // Xs visible

    #pragma unroll
    for (int k = 0; k < KNUM; ++k) {
      const int s = cb * 6 + k;
      // #1: build this wave's B-fragments in-register (R8-verified mapping)
      bf16x8 mb = *(const bf16x8*)((const char*)Ms
                    + (k * 32 + wsel * 16 + lw) * 64 + (((lg ^ msw2) & 3) << 4));
      bf16x8 bfrag[2];
      #pragma unroll
      for (int kk = 0; kk < 2; ++kk) {
        int ra = dt * 64 + kk * 32 + lw;
        int swa = (ra & 3) ^ ((ra >> 2) & 3);
        int off = ((lg ^ swa) & 3) << 4;
        bf16x8 afa = *(const bf16x8*)((const char*)Xs + ra * 64 + off);
        bf16x8 afb = *(const bf16x8*)((const char*)Xs + (ra + 16) * 64 + off);
        f32x4 da = __builtin_amdgcn_mfma_f32_16x16x32_bf16(afa, mb, z4, 0, 0, 0);
        f32x4 db = __builtin_amdgcn_mfma_f32_16x16x32_bf16(afb, mb, z4, 0, 0, 0);
        bfrag[kk] = pack8(da, db);
      }
      // #2: 16 MFMA, af2 streamed from wp3 (chunk C = s*32 + mh*16 + 2i + kk)
      const bf16_t* wpS = wp3 + ((long)(s * 32 + mh * 16) << 9) + (ln << 3);
      __builtin_amdgcn_s_setprio(1);
      #pragma unroll
      for (int i = 0; i < 8; ++i) {
        bf16x8 a0 = *(const bf16x8*)(wpS + ((2 * i + 0) << 9));
        acc[i] = __builtin_amdgcn_mfma_f32_16x16x32_bf16(a0, bfrag[0], acc[i], 0, 0, 0);
        bf16x8 a1 = *(const bf16x8*)(wpS + ((2 * i + 1) << 9));
        acc[i] = __builtin_amdgcn_mfma_f32_16x16x32_bf16(a1, bfrag[1], acc[i], 0, 0, 0);
      }
      __builtin_amdgcn_s_setprio(0);
    }
  }

  // epilogue: C/D map col=lane&15, row=(lane>>4)*4+reg [m89-verified]
  {
    int colb = wv * 16 + lw;             // 0..127
    int w = colb & 31;                   // = wsel*16 + lw
    if (w < VV) {
      float* ob = out + (long)n * 409600 + (t0 + dt) * 25 + w;
      const float* brow = biasmat + (n * 25 + w) * 256;
      #pragma unroll
      for (int i = 0; i < 8; ++i) {
        int m0 = (mh * 8 + i) * 16 + (lg << 2);
        #pragma unroll
        for (int r = 0; r < 4; ++r) {
          int m = m0 + r;
          ob[(long)m * 1600] = acc[i][r] + brow[m];
        }
      }
    }
  }
}

// ---------------- ws-free fp32 fallback (insurance) ----------------
__global__ __launch_bounds__(256) void fallback_kernel(
    const float* __restrict__ x, const float* __restrict__ A,
    const float* __restrict__ Bm, const float* __restrict__ lam_p,
    const float* __restrict__ W, const float* __restrict__ bvec,
    float* __restrict__ out)
{
  __shared__ __align__(16) float xs[CIN][28];
  __shared__ __align__(16) float Ms[KNUM][VV][28];   // [k][v][w] padded
  const int nt = blockIdx.x;
  const int n = nt >> 6, t = nt & 63;
  const int tid = threadIdx.x;
  const float lam = lam_p[0];

  const float* xp = x + (((long)(n * CIN + tid) * TDIM + t) * VV);
  #pragma unroll
  for (int v = 0; v < VV; ++v) xs[tid][v] = xp[v];
  xs[tid][25] = xs[tid][26] = xs[tid][27] = 0.f;
  for (int i = tid; i < KNUM * VV * VV; i += 256) {
    int k = i / (VV * VV);
    int r = i - k * VV * VV;
    int v = r / VV;
    int w = r - v * VV;
    Ms[k][v][w] = (k < ET) ? A[(k * VV + v) * VV + w]
                           : lam * Bm[(((n * ET) + (k - ET)) * VV + v) * VV + w];
    if (w == 24) { Ms[k][v][25] = Ms[k][v][26] = Ms[k][v][27] = 0.f; }
  }
  __syncthreads();

  float oacc[28] = {};
  for (int k = 0; k < KNUM; ++k) {
    float yv[28];
    float bv = bvec[(k << 8) + tid];
    #pragma unroll
    for (int v = 0; v < 28; ++v) yv[v] = 0.f;
    for (int ci = 0; ci < CIN; ++ci) {
      float wl = W[ci * KD + (k << 8) + tid];
      const f32x4* x4 = (const f32x4*)&xs[ci][0];
      #pragma unroll
      for (int q = 0; q < 7; ++q) {
        f32x4 xv = x4[q];
        yv[q*4+0] += wl*xv[0]; yv[q*4+1] += wl*xv[1];
        yv[q*4+2] += wl*xv[2]; yv[q*4+3] += wl*xv[3];
      }
    }
    #pragma unroll
    for (int v = 0; v < VV; ++v) {
      float yvv = yv[v] + bv;
      const f32x4* m4 = (const f32x4*)&Ms[k][v][0];
      #pragma unroll
      for (int q = 0; q < 7; ++q) {
        f32x4 mv = m4[q];
        oacc[q*4+0] += yvv*mv[0]; oacc[q*4+1] += yvv*mv[1];
        oacc[q*4+2] += yvv*mv[2]; oacc[q*4+3] += yvv*mv[3];
      }
    }
  }
  float* op = out + (((long)(n * COUT + tid) * TDIM + t) * VV);
  #pragma unroll
  for (int w = 0; w < VV; ++w) op[w] = oacc[w];
}

__global__ void copyA_kernel(const float* __restrict__ A, float* __restrict__ outA) {
  int i = blockIdx.x * 256 + threadIdx.x;
  if (i < ACNT) outA[i] = A[i];
}

extern "C" void kernel_launch(void* const* d_in, const int* in_sizes, int n_in,
                              void* d_out, int out_size, void* d_ws, size_t ws_size,
                              hipStream_t stream) {
  const float* x   = (const float*)d_in[0];
  const float* A   = (const float*)d_in[1];
  const float* Bm  = (const float*)d_in[2];
  const float* lam = (const float*)d_in[3];
  const float* W   = (const float*)d_in[4];
  const float* bv  = (const float*)d_in[5];
  float* out = (float*)d_out;

  if (d_ws != nullptr && ws_size >= WS_NEED) {
    bf16_t* wp3     = (bf16_t*)d_ws;
    float*  biasmat = (float*)((char*)d_ws + BIAS_OFF);
    constexpr int PREP_ITEMS = WP3_CHUNKS + NB * VV * COUT + ACNT;
    prep_kernel<<<(PREP_ITEMS + 255) / 256, 256, 0, stream>>>(A, Bm, lam, W, bv, wp3, biasmat, out + OUT0);
    fused_kernel<<<2 * NB * 16, 512, 0, stream>>>(x, A, Bm, lam, wp3, biasmat, out);
  } else {
    fallback_kernel<<<NB * TDIM, 256, 0, stream>>>(x, A, Bm, lam, W, bv, out);
    copyA_kernel<<<(ACNT + 255) / 256, 256, 0, stream>>>(A, out + OUT0);
  }
}

// Round 13
// 154.824 us; speedup vs baseline: 1.3381x; 1.3381x over previous
//
#include <hip/hip_runtime.h>
#include <hip/hip_bf16.h>
#include <stdint.h>

typedef __bf16 bf16_t;
typedef bf16_t bf16x8 __attribute__((ext_vector_type(8)));
typedef float f32x4 __attribute__((ext_vector_type(4)));

#define DEVI static __device__ __forceinline__

constexpr int NB = 32, CIN = 256, COUT = 256, KNUM = 6, ET = 3, TDIM = 64, VV = 25;
constexpr int KD   = KNUM * CIN;       // 1536 contraction dim (k,ci)
constexpr long OUT0 = (long)NB * COUT * TDIM * VV;  // 13107200 (x_sum elems)
constexpr int ACNT = ET * VV * VV;     // 1875 (A copy)

// wp3: W in fragment-order (R7-verified layout). 24 steps x 2048 chunks x 16B.
constexpr int NSTEP = 24;
constexpr int WP3_CHUNKS = NSTEP * 2048;
constexpr size_t WP3_BYTES = (size_t)WP3_CHUNKS * 16;       // 768 KB
// Mw: lam-folded, zero-padded, XOR-swizzled M table, per n: 6k x 32w x 32v bf16
constexpr int MW_PER_N   = KNUM * 32 * 32;                  // 6144 elems (12288 B)
constexpr size_t MW_OFF    = WP3_BYTES;
constexpr size_t MW_BYTES  = (size_t)NB * MW_PER_N * 2;     // 384 KB
constexpr size_t BIAS_OFF  = MW_OFF + MW_BYTES;
constexpr size_t BIAS_BYTES = (size_t)NB * VV * COUT * 4;   // bias [n][w][c] f32
constexpr size_t WS_NEED   = BIAS_OFF + BIAS_BYTES;

DEVI unsigned packbf(float lo, float hi) {
  unsigned short a = __builtin_bit_cast(unsigned short, (bf16_t)lo);
  unsigned short b = __builtin_bit_cast(unsigned short, (bf16_t)hi);
  return ((unsigned)b << 16) | (unsigned)a;
}

// ---------------- prep: wp3 + Mw + bias table + A copy ----------------------
__global__ __launch_bounds__(256) void prep_kernel(
    const float* __restrict__ A, const float* __restrict__ Bm,
    const float* __restrict__ lam_p, const float* __restrict__ W,
    const float* __restrict__ bvec, bf16_t* __restrict__ wp3,
    bf16_t* __restrict__ Mw, float* __restrict__ biasmat,
    float* __restrict__ outA)
{
  int idx = blockIdx.x * 256 + threadIdx.x;
  constexpr int S1 = WP3_CHUNKS;            // 49152
  constexpr int S2 = S1 + NB * MW_PER_N;    // +196608
  constexpr int S3 = S2 + NB * VV * COUT;   // +204800
  constexpr int S4 = S3 + ACNT;
  if (idx < S1) {
    int s  = idx >> 11;
    int r  = idx & 2047;
    int mi = r >> 7;
    int kk = (r >> 6) & 1;
    int ln = r & 63;
    int lg = ln >> 4, lw = ln & 15;
    int cb = s / 6, k = s - cb * 6;
    int cibase = cb * 64 + (lg + 4 * kk) * 8;
    int col = (k << 8) + mi * 16 + lw;
    bf16_t* dst = wp3 + ((long)idx << 3);
    #pragma unroll
    for (int e = 0; e < 8; ++e)
      dst[e] = (bf16_t)W[(cibase + e) * KD + col];
  } else if (idx < S2) {
    int j = idx - S1;
    int n = j / MW_PER_N;
    int r2 = j - n * MW_PER_N;
    int k = r2 >> 10, w = (r2 >> 5) & 31, v = r2 & 31;
    float lam = lam_p[0];
    float val = 0.f;
    if (w < VV && v < VV)
      val = (k < ET) ? A[(k * VV + v) * VV + w]
                     : lam * Bm[(((n * ET) + (k - ET)) * VV + v) * VV + w];
    int sw2 = (w & 3) ^ ((w >> 2) & 3);
    long byteoff = (long)n * 12288 + (k * 32 + w) * 64
                 + ((((v >> 3) ^ sw2) & 3) << 4) + ((v & 7) << 1);
    *(bf16_t*)((char*)Mw + byteoff) = (bf16_t)val;
  } else if (idx < S3) {
    // bias[n][w][c] = sum_k b[k*256+c] * colsum_v M[n,k,v,w] (lam folded)
    int j = idx - S2;
    int c = j & 255;
    int nw = j >> 8;
    int w = nw % VV;
    int n = nw / VV;
    float lam = lam_p[0];
    float s = 0.f;
    for (int k = 0; k < KNUM; ++k) {
      float sk = 0.f;
      if (k < ET) {
        for (int v = 0; v < VV; ++v) sk += A[(k * VV + v) * VV + w];
      } else {
        for (int v = 0; v < VV; ++v) sk += Bm[(((n * ET) + (k - ET)) * VV + v) * VV + w];
        sk *= lam;
      }
      s += bvec[(k << 8) + c] * sk;
    }
    biasmat[j] = s;
  } else if (idx < S4) {
    int j = idx - S3;
    outA[j] = A[j];   // second tuple output: A passthrough
  }
}

// ---------------- fused kernel: BN=64 t-split, 2 k-steps per barrier ---------
// Grid 1024: block = (n, t-pair). Per interval (2 k's): #1 for both k's
// (Xs x Mw-frags -> Bs quad-buffer, XOR swizzle), ONE barrier, #2 for both
// (af2 from wp3 frag-order, kk-split to cap regs). 20 barriers/block total.
// LDS 40 KB; acc 4x2 (32 AGPR) + ~65 VGPR working set.
__global__ __launch_bounds__(512, 4) void fused_kernel(
    const float* __restrict__ x, const bf16_t* __restrict__ Mw,
    const bf16_t* __restrict__ wp3, const float* __restrict__ biasmat,
    float* __restrict__ out)
{
  __shared__ __align__(16) bf16_t Bs[4 * 64 * 64];   // 32 KB: [interval parity][khalf][col][ci]
  __shared__ __align__(16) bf16_t Xs[128 * 32];      // 8 KB [row=dt*64+ci][v] swizzled

  const int b = blockIdx.x;
  const int n = b >> 5;                  // 0..31
  const int t0 = (b & 31) << 1;          // t-pair
  const int tid = threadIdx.x;
  const int wv = tid >> 6, ln = tid & 63;
  const int lw = ln & 15, lg = ln >> 4;

  f32x4 acc[4][2] = {};
  const int m_base = (wv >> 1) * 64;
  const int mb4 = (wv >> 1) * 4;         // mi base for A-fragments
  const int n_base = (wv & 1) * 32;      // col base within 64
  const f32x4 z4 = {0.f, 0.f, 0.f, 0.f};
  const int msw2 = (lw & 3) ^ ((lw >> 2) & 3);
  const char* mwb = (const char*)Mw + (long)n * 12288;

  #pragma unroll 1
  for (int cb = 0; cb < 4; ++cb) {
    __syncthreads();   // prior readers of Xs done
    // stage Xs (R10-verified): tid<256, row = tid>>1 (0..127), gh = tid&1
    if (tid < 256) {
      int row = tid >> 1, gh = tid & 1;
      int dt = row >> 6, ci = row & 63;
      const float* xp = x + ((long)(n * CIN + cb * 64 + ci) * TDIM + t0 + dt) * VV + gh * 16;
      float xv[16];
      #pragma unroll
      for (int v = 0; v < 16; ++v) xv[v] = 0.f;
      if (gh == 0) {
        #pragma unroll
        for (int v = 0; v < 16; ++v) xv[v] = xp[v];
      } else {
        #pragma unroll
        for (int v = 0; v < 9; ++v) xv[v] = xp[v];
      }
      int sw = (row & 3) ^ ((row >> 2) & 3);
      #pragma unroll
      for (int g2 = 0; g2 < 2; ++g2) {
        int g = gh * 2 + g2;
        char* base = (char*)Xs + row * 64 + ((g ^ sw) & 3) * 16;
        #pragma unroll
        for (int p = 0; p < 4; ++p) {
          int vl = g2 * 8 + p * 2;
          *(unsigned*)(base + p * 4) = packbf(xv[vl], xv[vl + 1]);
        }
      }
    }
    __syncthreads();   // Xs visible

    #pragma unroll
    for (int ki = 0; ki < 3; ++ki) {     // interval of 2 k's
      const int ii = cb * 3 + ki;
      const int bufI = (ii & 1) * 8192;  // elems
      // ---- #1 for both k's of the interval -> Bs ----
      #pragma unroll
      for (int kh = 0; kh < 2; ++kh) {
        const int k = ki * 2 + kh;
        const int bufk = bufI + kh * 4096;
        bf16x8 mb0 = *(const bf16x8*)(mwb + (k * 32 + lw) * 64 + (((lg ^ msw2) & 3) << 4));
        bf16x8 mb1 = *(const bf16x8*)(mwb + (k * 32 + 16 + lw) * 64 + (((lg ^ msw2) & 3) << 4));
        int arow = wv * 16 + lw;
        int sw = (arow & 3) ^ ((arow >> 2) & 3);
        bf16x8 af = *(const bf16x8*)((const char*)Xs + arow * 64 + (((lg ^ sw) & 3) << 4));
        f32x4 d0 = __builtin_amdgcn_mfma_f32_16x16x32_bf16(af, mb0, z4, 0, 0, 0);
        f32x4 d1 = __builtin_amdgcn_mfma_f32_16x16x32_bf16(af, mb1, z4, 0, 0, 0);
        int rbase = wv * 16 + (lg << 2);
        int dt = rbase >> 6, ci0 = rbase & 63;
        int r0 = dt * 32 + lw;
        int g0 = ((ci0 >> 3) ^ (r0 & 7)) & 7;
        uint2 p0; p0.x = packbf(d0[0], d0[1]); p0.y = packbf(d0[2], d0[3]);
        *(uint2*)((char*)Bs + bufk * 2 + r0 * 128 + (g0 << 4) + ((ci0 << 1) & 15)) = p0;
        uint2 p1; p1.x = packbf(d1[0], d1[1]); p1.y = packbf(d1[2], d1[3]);
        *(uint2*)((char*)Bs + bufk * 2 + (r0 + 16) * 128 + (g0 << 4) + ((ci0 << 1) & 15)) = p1;
      }
      __syncthreads();   // both k-tiles of the interval ready (1 barrier / 2 steps)

      // ---- #2 for both k's ----
      __builtin_amdgcn_s_setprio(1);
      #pragma unroll
      for (int kh = 0; kh < 2; ++kh) {
        const int k = ki * 2 + kh;
        const int s = cb * 6 + k;
        const int bufk = bufI + kh * 4096;
        #pragma unroll
        for (int kk = 0; kk < 2; ++kk) {
          bf16x8 af2[4];
          #pragma unroll
          for (int i = 0; i < 4; ++i)
            af2[i] = *(const bf16x8*)(wp3 + (((long)((s * 16 + mb4 + i) * 2 + kk) * 64 + ln) << 3));
          bf16x8 bf2[2];
          #pragma unroll
          for (int j = 0; j < 2; ++j) {
            int rr = n_base + j * 16 + lw;
            int gg = ((kk * 4 + lg) ^ (rr & 7)) & 7;
            bf2[j] = *(const bf16x8*)((const char*)Bs + bufk * 2 + rr * 128 + (gg << 4));
          }
          #pragma unroll
          for (int i = 0; i < 4; ++i)
            #pragma unroll
            for (int j = 0; j < 2; ++j)
              acc[i][j] = __builtin_amdgcn_mfma_f32_16x16x32_bf16(af2[i], bf2[j], acc[i][j], 0, 0, 0);
        }
      }
      __builtin_amdgcn_s_setprio(0);
    }
  }

  // epilogue: C/D map col=lane&15, row=(lane>>4)*4+reg [m89-verified]
  #pragma unroll
  for (int j = 0; j < 2; ++j) {
    int colb = n_base + j * 16 + lw;         // 0..63
    int dt = colb >> 5, w = colb & 31;
    if (w < VV) {
      float* ob = out + (long)n * 409600 + (t0 + dt) * 25 + w;
      const float* brow = biasmat + (n * 25 + w) * 256;
      #pragma unroll
      for (int i = 0; i < 4; ++i) {
        int mb = m_base + i * 16 + (lg << 2);
        #pragma unroll
        for (int r = 0; r < 4; ++r) {
          int m = mb + r;
          ob[(long)m * 1600] = acc[i][j][r] + brow[m];
        }
      }
    }
  }
}

// ---------------- ws-free fp32 fallback (insurance) ----------------
__global__ __launch_bounds__(256) void fallback_kernel(
    const float* __restrict__ x, const float* __restrict__ A,
    const float* __restrict__ Bm, const float* __restrict__ lam_p,
    const float* __restrict__ W, const float* __restrict__ bvec,
    float* __restrict__ out)
{
  __shared__ __align__(16) float xs[CIN][28];
  __shared__ __align__(16) float Ms[KNUM][VV][28];   // [k][v][w] padded
  const int nt = blockIdx.x;
  const int n = nt >> 6, t = nt & 63;
  const int tid = threadIdx.x;
  const float lam = lam_p[0];

  const float* xp = x + (((long)(n * CIN + tid) * TDIM + t) * VV);
  #pragma unroll
  for (int v = 0; v < VV; ++v) xs[tid][v] = xp[v];
  xs[tid][25] = xs[tid][26] = xs[tid][27] = 0.f;
  for (int i = tid; i < KNUM * VV * VV; i += 256) {
    int k = i / (VV * VV);
    int r = i - k * VV * VV;
    int v = r / VV;
    int w = r - v * VV;
    Ms[k][v][w] = (k < ET) ? A[(k * VV + v) * VV + w]
                           : lam * Bm[(((n * ET) + (k - ET)) * VV + v) * VV + w];
    if (w == 24) { Ms[k][v][25] = Ms[k][v][26] = Ms[k][v][27] = 0.f; }
  }
  __syncthreads();

  float oacc[28] = {};
  for (int k = 0; k < KNUM; ++k) {
    float yv[28];
    float bv = bvec[(k << 8) + tid];
    #pragma unroll
    for (int v = 0; v < 28; ++v) yv[v] = 0.f;
    for (int ci = 0; ci < CIN; ++ci) {
      float wl = W[ci * KD + (k << 8) + tid];
      const f32x4* x4 = (const f32x4*)&xs[ci][0];
      #pragma unroll
      for (int q = 0; q < 7; ++q) {
        f32x4 xv = x4[q];
        yv[q*4+0] += wl*xv[0]; yv[q*4+1] += wl*xv[1];
        yv[q*4+2] += wl*xv[2]; yv[q*4+3] += wl*xv[3];
      }
    }
    #pragma unroll
    for (int v = 0; v < VV; ++v) {
      float yvv = yv[v] + bv;
      const f32x4* m4 = (const f32x4*)&Ms[k][v][0];
      #pragma unroll
      for (int q = 0; q < 7; ++q) {
        f32x4 mv = m4[q];
        oacc[q*4+0] += yvv*mv[0]; oacc[q*4+1] += yvv*mv[1];
        oacc[q*4+2] += yvv*mv[2]; oacc[q*4+3] += yvv*mv[3];
      }
    }
  }
  float* op = out + (((long)(n * COUT + tid) * TDIM + t) * VV);
  #pragma unroll
  for (int w = 0; w < VV; ++w) op[w] = oacc[w];
}

__global__ void copyA_kernel(const float* __restrict__ A, float* __restrict__ outA) {
  int i = blockIdx.x * 256 + threadIdx.x;
  if (i < ACNT) outA[i] = A[i];
}

extern "C" void kernel_launch(void* const* d_in, const int* in_sizes, int n_in,
                              void* d_out, int out_size, void* d_ws, size_t ws_size,
                              hipStream_t stream) {
  const float* x   = (const float*)d_in[0];
  const float* A   = (const float*)d_in[1];
  const float* Bm  = (const float*)d_in[2];
  const float* lam = (const float*)d_in[3];
  const float* W   = (const float*)d_in[4];
  const float* bv  = (const float*)d_in[5];
  float* out = (float*)d_out;

  if (d_ws != nullptr && ws_size >= WS_NEED) {
    bf16_t* wp3     = (bf16_t*)d_ws;
    bf16_t* Mw      = (bf16_t*)((char*)d_ws + MW_OFF);
    float*  biasmat = (float*)((char*)d_ws + BIAS_OFF);
    constexpr int PREP_ITEMS = WP3_CHUNKS + NB * MW_PER_N + NB * VV * COUT + ACNT;
    prep_kernel<<<(PREP_ITEMS + 255) / 256, 256, 0, stream>>>(A, Bm, lam, W, bv, wp3, Mw, biasmat, out + OUT0);
    fused_kernel<<<NB * 32, 512, 0, stream>>>(x, Mw, wp3, biasmat, out);
  } else {
    fallback_kernel<<<NB * TDIM, 256, 0, stream>>>(x, A, Bm, lam, W, bv, out);
    copyA_kernel<<<(ACNT + 255) / 256, 256, 0, stream>>>(A, out + OUT0);
  }
}

// Round 14
// 89.521 us; speedup vs baseline: 2.3143x; 1.7295x over previous
//
#include <hip/hip_runtime.h>
#include <hip/hip_bf16.h>
#include <stdint.h>

typedef __bf16 bf16_t;
typedef bf16_t bf16x8 __attribute__((ext_vector_type(8)));
typedef float f32x4 __attribute__((ext_vector_type(4)));

#define DEVI static __device__ __forceinline__

constexpr int NB = 32, CIN = 256, COUT = 256, KNUM = 6, ET = 3, TDIM = 64, VV = 25;
constexpr int KD   = KNUM * CIN;       // 1536 contraction dim (k,ci)
constexpr long OUT0 = (long)NB * COUT * TDIM * VV;  // 13107200 (x_sum elems)
constexpr int ACNT = ET * VV * VV;     // 1875 (A copy)

// wp3: W in fragment-order. 24 steps x 2048 chunks x 16B = 768 KB. (R7 layout)
constexpr int NSTEP = 24;              // 4 cb x 6 k
constexpr int WP3_CHUNKS = NSTEP * 2048;
constexpr size_t WP3_BYTES  = (size_t)WP3_CHUNKS * 16;      // 768 KB
constexpr size_t BIAS_OFF   = WP3_BYTES;
constexpr size_t BIAS_BYTES = (size_t)NB * VV * COUT * 4;   // bias [n][w][c] f32
constexpr size_t WS_NEED    = BIAS_OFF + BIAS_BYTES;

DEVI unsigned packbf(float lo, float hi) {
  unsigned short a = __builtin_bit_cast(unsigned short, (bf16_t)lo);
  unsigned short b = __builtin_bit_cast(unsigned short, (bf16_t)hi);
  return ((unsigned)b << 16) | (unsigned)a;
}

// ---------------- prep: wp3 fragment-layout + bias table + A copy ----------
__global__ __launch_bounds__(256) void prep_kernel(
    const float* __restrict__ A, const float* __restrict__ Bm,
    const float* __restrict__ lam_p, const float* __restrict__ W,
    const float* __restrict__ bvec, bf16_t* __restrict__ wp3,
    float* __restrict__ biasmat, float* __restrict__ outA)
{
  int idx = blockIdx.x * 256 + threadIdx.x;
  constexpr int S1 = WP3_CHUNKS;            // 49152 (one 16B chunk per thread)
  constexpr int S2 = S1 + NB * VV * COUT;   // +204800
  constexpr int S3 = S2 + ACNT;
  if (idx < S1) {
    int s  = idx >> 11;
    int r  = idx & 2047;
    int mi = r >> 7;
    int kk = (r >> 6) & 1;
    int ln = r & 63;
    int lg = ln >> 4, lw = ln & 15;
    int cb = s / 6, k = s - cb * 6;
    int cibase = cb * 64 + (lg + 4 * kk) * 8;
    int col = (k << 8) + mi * 16 + lw;
    bf16_t* dst = wp3 + ((long)idx << 3);
    #pragma unroll
    for (int e = 0; e < 8; ++e)
      dst[e] = (bf16_t)W[(cibase + e) * KD + col];
  } else if (idx < S2) {
    // bias[n][w][c] = sum_k b[k*256+c] * S[n,k,w],  S = col-sum of M (lam folded)
    int j = idx - S1;
    int c = j & 255;
    int nw = j >> 8;
    int w = nw % VV;
    int n = nw / VV;
    float lam = lam_p[0];
    float s = 0.f;
    for (int k = 0; k < KNUM; ++k) {
      float sk = 0.f;
      if (k < ET) {
        for (int v = 0; v < VV; ++v) sk += A[(k * VV + v) * VV + w];
      } else {
        for (int v = 0; v < VV; ++v) sk += Bm[(((n * ET) + (k - ET)) * VV + v) * VV + w];
        sk *= lam;
      }
      s += bvec[(k << 8) + c] * sk;
    }
    biasmat[j] = s;
  } else if (idx < S3) {
    int j = idx - S2;
    outA[j] = A[j];   // second tuple output: A passthrough
  }
}

// ---------------- fused kernel (R7 structure + 3 surgical edits) -------------
// Per step (cb,k): af2 <- wp3 (global, frag-order); MFMA#1 Xs x Ms -> Bs[buf]
// (XOR-swizzled, dbuf, uint2 b64 writes); ONE barrier; MFMA#2 (setprio).
// Edits vs R7: (1) redundant cb-top barrier removed (k=5's barrier already
// orders Xs reads vs restage), (2) uint2 pack-writes, (3) XCD-aware swizzle.
__global__ __launch_bounds__(512, 2) void fused_kernel(
    const float* __restrict__ x, const float* __restrict__ A,
    const float* __restrict__ Bm, const float* __restrict__ lam_p,
    const bf16_t* __restrict__ wp3, const float* __restrict__ biasmat,
    float* __restrict__ out)
{
  __shared__ __align__(16) bf16_t Bs[2 * 128 * 64];  // 32 KB dbuf, rows 128B, XOR-swz
  __shared__ __align__(16) bf16_t Xs[256 * 32];      // 16 KB [row=dt*64+ci][v] swizzled
  __shared__ __align__(16) bf16_t Ms[KNUM * 32 * 32];// 12 KB [k][w][v] swizzled, zero-pad

  // XCD-aware swizzle (T1): grid 512 = 8 XCDs x 64; XCD j -> works [j*64,(j+1)*64)
  const int b = (blockIdx.x & 7) * 64 + (blockIdx.x >> 3);
  const int n = b >> 4;                  // 0..31
  const int t0 = (b & 15) << 2;          // t-group of 4
  const int tid = threadIdx.x;
  const int wv = tid >> 6, ln = tid & 63;
  const int lw = ln & 15, lg = ln >> 4;
  const float lam = lam_p[0];

  // stage Ms once: row R=k*32+w (64B), group-XOR sw2=(w&3)^((w>>2)&3)
  for (int i = tid; i < KNUM * 32 * 32; i += 512) {
    int R = i >> 5, v = i & 31;
    int k = i >> 10, w = (i >> 5) & 31;
    float val = 0.f;
    if (w < VV && v < VV)
      val = (k < ET) ? A[(k * VV + v) * VV + w]
                     : lam * Bm[(((n * ET) + (k - ET)) * VV + v) * VV + w];
    int sw2 = (w & 3) ^ ((w >> 2) & 3);
    int byteoff = R * 64 + ((((v >> 3) ^ sw2) & 3) << 4) + ((v & 7) << 1);
    *(bf16_t*)((char*)Ms + byteoff) = (bf16_t)val;
  }

  f32x4 acc[4][4] = {};
  const int m_base = (wv >> 1) * 64;
  const int mb4 = (wv >> 1) * 4;         // mi base for A-fragments
  const int n_base = (wv & 1) * 64;
  const f32x4 z4 = {0.f, 0.f, 0.f, 0.f};
  const int msw2 = (lw & 3) ^ ((lw >> 2) & 3);   // Ms read swizzle

  #pragma unroll 1
  for (int cb = 0; cb < 4; ++cb) {
    // stage Xs (R7 verbatim). No cb-top barrier needed: every wave here has
    // passed step k=5's barrier of the previous cb, which all Xs reads precede.
    if (tid < 256) {
      int ci = tid >> 2, dt = tid & 3;
      const float* xp = x + ((long)(n * CIN + cb * 64 + ci) * TDIM + t0 + dt) * VV;
      float xv[25];
      #pragma unroll
      for (int v = 0; v < VV; ++v) xv[v] = xp[v];
      int row = dt * 64 + ci;
      int sw = (row & 3) ^ ((row >> 2) & 3);
      #pragma unroll
      for (int g = 0; g < 4; ++g) {
        char* base = (char*)Xs + row * 64 + ((g ^ sw) & 3) * 16;
        #pragma unroll
        for (int p = 0; p < 4; ++p) {
          int v0 = g * 8 + p * 2;
          float lo = (v0     < VV) ? xv[v0 < VV ? v0 : 0]     : 0.f;
          float hi = (v0 + 1 < VV) ? xv[v0 + 1 < VV ? v0 + 1 : 0] : 0.f;
          *(unsigned*)(base + p * 4) = packbf(lo, hi);
        }
      }
    }
    __syncthreads();   // Xs (and first-iter Ms) visible

    #pragma unroll 1
    for (int k = 0; k < KNUM; ++k) {
      const int s = cb * 6 + k;
      const int buf = (s & 1) * (128 * 64);
      // A fragments direct global->VGPR (coalesced 16B/lane, L2-hot)
      bf16x8 af2[2][4];
      const bf16_t* wpS = wp3 + (((long)s * 2048 + (long)mb4 * 128 + ln) << 3);
      #pragma unroll
      for (int kk = 0; kk < 2; ++kk)
        #pragma unroll
        for (int i = 0; i < 4; ++i)
          af2[kk][i] = *(const bf16x8*)(wpS + ((i * 128 + kk * 64) << 3));

      // MFMA#1: Xs x Ms -> Bs[buf]  (uint2 b64 pack-writes, 8B-aligned)
      bf16x8 mb0 = *(const bf16x8*)((const char*)Ms + (k * 32 + lw) * 64 + (((lg ^ msw2) & 3) << 4));
      bf16x8 mb1 = *(const bf16x8*)((const char*)Ms + (k * 32 + 16 + lw) * 64 + (((lg ^ msw2) & 3) << 4));
      #pragma unroll
      for (int rt = 0; rt < 2; ++rt) {
        int arow = wv * 32 + rt * 16 + lw;
        int sw = (arow & 3) ^ ((arow >> 2) & 3);
        int off = ((lg ^ sw) & 3) << 4;
        bf16x8 af = *(const bf16x8*)((const char*)Xs + arow * 64 + off);
        f32x4 d0 = __builtin_amdgcn_mfma_f32_16x16x32_bf16(af, mb0, z4, 0, 0, 0);
        f32x4 d1 = __builtin_amdgcn_mfma_f32_16x16x32_bf16(af, mb1, z4, 0, 0, 0);
        int rbase = wv * 32 + rt * 16 + (lg << 2);
        int dt = rbase >> 6, ci0 = rbase & 63;
        int r0 = dt * 32 + lw;
        int g0 = ((ci0 >> 3) ^ (r0 & 7)) & 7;
        uint2 p0; p0.x = packbf(d0[0], d0[1]); p0.y = packbf(d0[2], d0[3]);
        *(uint2*)((char*)(Bs + buf) + r0 * 128 + (g0 << 4) + ((ci0 << 1) & 15)) = p0;
        uint2 p1; p1.x = packbf(d1[0], d1[1]); p1.y = packbf(d1[2], d1[3]);
        *(uint2*)((char*)(Bs + buf) + (r0 + 16) * 128 + (g0 << 4) + ((ci0 << 1) & 15)) = p1;
      }
      __syncthreads();   // Bs[buf] ready (single barrier per step; dbuf)

      // MFMA#2: acc += af2 x Bs[buf]
      __builtin_amdgcn_s_setprio(1);
      #pragma unroll
      for (int kk = 0; kk < 2; ++kk) {
        bf16x8 bf2[4];
        #pragma unroll
        for (int j = 0; j < 4; ++j) {
          int rr = n_base + j * 16 + lw;
          int gg = ((kk * 4 + lg) ^ (rr & 7)) & 7;
          bf2[j] = *(const bf16x8*)((const char*)(Bs + buf) + rr * 128 + (gg << 4));
        }
        #pragma unroll
        for (int i = 0; i < 4; ++i)
          #pragma unroll
          for (int j = 0; j < 4; ++j)
            acc[i][j] = __builtin_amdgcn_mfma_f32_16x16x32_bf16(af2[kk][i], bf2[j], acc[i][j], 0, 0, 0);
      }
      __builtin_amdgcn_s_setprio(0);
    }
  }

  // epilogue: C/D map col=lane&15, row=(lane>>4)*4+reg [m89-verified]
  #pragma unroll
  for (int j = 0; j < 4; ++j) {
    int colb = n_base + j * 16 + lw;         // 0..127
    int dt = colb >> 5, w = colb & 31;
    if (w < VV) {
      float* ob = out + (long)n * 409600 + (t0 + dt) * 25 + w;
      const float* brow = biasmat + (n * 25 + w) * 256;
      #pragma unroll
      for (int i = 0; i < 4; ++i) {
        int mb = m_base + i * 16 + (lg << 2);
        #pragma unroll
        for (int r = 0; r < 4; ++r) {
          int m = mb + r;
          ob[(long)m * 1600] = acc[i][j][r] + brow[m];
        }
      }
    }
  }
}

// ---------------- ws-free fp32 fallback (insurance) ----------------
__global__ __launch_bounds__(256) void fallback_kernel(
    const float* __restrict__ x, const float* __restrict__ A,
    const float* __restrict__ Bm, const float* __restrict__ lam_p,
    const float* __restrict__ W, const float* __restrict__ bvec,
    float* __restrict__ out)
{
  __shared__ __align__(16) float xs[CIN][28];
  __shared__ __align__(16) float Ms[KNUM][VV][28];   // [k][v][w] padded
  const int nt = blockIdx.x;
  const int n = nt >> 6, t = nt & 63;
  const int tid = threadIdx.x;
  const float lam = lam_p[0];

  const float* xp = x + (((long)(n * CIN + tid) * TDIM + t) * VV);
  #pragma unroll
  for (int v = 0; v < VV; ++v) xs[tid][v] = xp[v];
  xs[tid][25] = xs[tid][26] = xs[tid][27] = 0.f;
  for (int i = tid; i < KNUM * VV * VV; i += 256) {
    int k = i / (VV * VV);
    int r = i - k * VV * VV;
    int v = r / VV;
    int w = r - v * VV;
    Ms[k][v][w] = (k < ET) ? A[(k * VV + v) * VV + w]
                           : lam * Bm[(((n * ET) + (k - ET)) * VV + v) * VV + w];
    if (w == 24) { Ms[k][v][25] = Ms[k][v][26] = Ms[k][v][27] = 0.f; }
  }
  __syncthreads();

  float oacc[28] = {};
  for (int k = 0; k < KNUM; ++k) {
    float yv[28];
    float bv = bvec[(k << 8) + tid];
    #pragma unroll
    for (int v = 0; v < 28; ++v) yv[v] = 0.f;
    for (int ci = 0; ci < CIN; ++ci) {
      float wl = W[ci * KD + (k << 8) + tid];
      const f32x4* x4 = (const f32x4*)&xs[ci][0];
      #pragma unroll
      for (int q = 0; q < 7; ++q) {
        f32x4 xv = x4[q];
        yv[q*4+0] += wl*xv[0]; yv[q*4+1] += wl*xv[1];
        yv[q*4+2] += wl*xv[2]; yv[q*4+3] += wl*xv[3];
      }
    }
    #pragma unroll
    for (int v = 0; v < VV; ++v) {
      float yvv = yv[v] + bv;
      const f32x4* m4 = (const f32x4*)&Ms[k][v][0];
      #pragma unroll
      for (int q = 0; q < 7; ++q) {
        f32x4 mv = m4[q];
        oacc[q*4+0] += yvv*mv[0]; oacc[q*4+1] += yvv*mv[1];
        oacc[q*4+2] += yvv*mv[2]; oacc[q*4+3] += yvv*mv[3];
      }
    }
  }
  float* op = out + (((long)(n * COUT + tid) * TDIM + t) * VV);
  #pragma unroll
  for (int w = 0; w < VV; ++w) op[w] = oacc[w];
}

__global__ void copyA_kernel(const float* __restrict__ A, float* __restrict__ outA) {
  int i = blockIdx.x * 256 + threadIdx.x;
  if (i < ACNT) outA[i] = A[i];
}

extern "C" void kernel_launch(void* const* d_in, const int* in_sizes, int n_in,
                              void* d_out, int out_size, void* d_ws, size_t ws_size,
                              hipStream_t stream) {
  const float* x   = (const float*)d_in[0];
  const float* A   = (const float*)d_in[1];
  const float* Bm  = (const float*)d_in[2];
  const float* lam = (const float*)d_in[3];
  const float* W   = (const float*)d_in[4];
  const float* bv  = (const float*)d_in[5];
  float* out = (float*)d_out;

  if (d_ws != nullptr && ws_size >= WS_NEED) {
    bf16_t* wp3     = (bf16_t*)d_ws;
    float*  biasmat = (float*)((char*)d_ws + BIAS_OFF);
    constexpr int PREP_ITEMS = WP3_CHUNKS + NB * VV * COUT + ACNT;
    prep_kernel<<<(PREP_ITEMS + 255) / 256, 256, 0, stream>>>(A, Bm, lam, W, bv, wp3, biasmat, out + OUT0);
    fused_kernel<<<NB * 16, 512, 0, stream>>>(x, A, Bm, lam, wp3, biasmat, out);
  } else {
    fallback_kernel<<<NB * TDIM, 256, 0, stream>>>(x, A, Bm, lam, W, bv, out);
    copyA_kernel<<<(ACNT + 255) / 256, 256, 0, stream>>>(A, out + OUT0);
  }
}

// Round 15
// 77.277 us; speedup vs baseline: 2.6809x; 1.1584x over previous
//
#include <hip/hip_runtime.h>
#include <hip/hip_bf16.h>
#include <stdint.h>

typedef __bf16 bf16_t;
typedef bf16_t bf16x8 __attribute__((ext_vector_type(8)));
typedef float f32x4 __attribute__((ext_vector_type(4)));

#define DEVI static __device__ __forceinline__

constexpr int NB = 32, CIN = 256, COUT = 256, KNUM = 6, ET = 3, TDIM = 64, VV = 25;
constexpr int KD   = KNUM * CIN;       // 1536 contraction dim (k,ci)
constexpr long OUT0 = (long)NB * COUT * TDIM * VV;  // 13107200 (x_sum elems)
constexpr int ACNT = ET * VV * VV;     // 1875 (A copy)

// wp3: W in fragment-order. 24 steps x 2048 chunks x 16B = 768 KB. (R7 layout)
constexpr int NSTEP = 24;              // 4 cb x 6 k
constexpr int WP3_CHUNKS = NSTEP * 2048;
constexpr size_t WP3_BYTES  = (size_t)WP3_CHUNKS * 16;      // 768 KB
constexpr size_t BIAS_OFF   = WP3_BYTES;
constexpr size_t BIAS_BYTES = (size_t)NB * VV * COUT * 4;   // bias [n][w][c] f32
constexpr size_t WS_NEED    = BIAS_OFF + BIAS_BYTES;

DEVI unsigned packbf(float lo, float hi) {
  unsigned short a = __builtin_bit_cast(unsigned short, (bf16_t)lo);
  unsigned short b = __builtin_bit_cast(unsigned short, (bf16_t)hi);
  return ((unsigned)b << 16) | (unsigned)a;
}

// ---------------- prep: wp3 fragment-layout + bias table + A copy ----------
__global__ __launch_bounds__(256) void prep_kernel(
    const float* __restrict__ A, const float* __restrict__ Bm,
    const float* __restrict__ lam_p, const float* __restrict__ W,
    const float* __restrict__ bvec, bf16_t* __restrict__ wp3,
    float* __restrict__ biasmat, float* __restrict__ outA)
{
  int idx = blockIdx.x * 256 + threadIdx.x;
  constexpr int S1 = WP3_CHUNKS;            // 49152 (one 16B chunk per thread)
  constexpr int S2 = S1 + NB * VV * COUT;   // +204800
  constexpr int S3 = S2 + ACNT;
  if (idx < S1) {
    int s  = idx >> 11;
    int r  = idx & 2047;
    int mi = r >> 7;
    int kk = (r >> 6) & 1;
    int ln = r & 63;
    int lg = ln >> 4, lw = ln & 15;
    int cb = s / 6, k = s - cb * 6;
    int cibase = cb * 64 + (lg + 4 * kk) * 8;
    int col = (k << 8) + mi * 16 + lw;
    bf16_t* dst = wp3 + ((long)idx << 3);
    #pragma unroll
    for (int e = 0; e < 8; ++e)
      dst[e] = (bf16_t)W[(cibase + e) * KD + col];
  } else if (idx < S2) {
    // bias[n][w][c] = sum_k b[k*256+c] * S[n,k,w],  S = col-sum of M (lam folded)
    int j = idx - S1;
    int c = j & 255;
    int nw = j >> 8;
    int w = nw % VV;
    int n = nw / VV;
    float lam = lam_p[0];
    float s = 0.f;
    for (int k = 0; k < KNUM; ++k) {
      float sk = 0.f;
      if (k < ET) {
        for (int v = 0; v < VV; ++v) sk += A[(k * VV + v) * VV + w];
      } else {
        for (int v = 0; v < VV; ++v) sk += Bm[(((n * ET) + (k - ET)) * VV + v) * VV + w];
        sk *= lam;
      }
      s += bvec[(k << 8) + c] * sk;
    }
    biasmat[j] = s;
  } else if (idx < S3) {
    int j = idx - S2;
    outA[j] = A[j];   // second tuple output: A passthrough
  }
}

// ---------------- fused kernel (R7 structure; af2 kk-split for occupancy) ----
// Per step (cb,k): af2[kk=0] <- wp3 at step top (hidden under #1); MFMA#1
// Xs x Ms -> Bs[buf] (XOR-swizzled, dbuf); ONE barrier; MFMA#2 kk=0 with
// prefetched frags, then kk=1 frags loaded at use (TLP-covered at 4 waves/SIMD).
// Peak A-frag liveness 32->16 VGPR => total ~120 <= 128 tier => 4 waves/SIMD.
__global__ __launch_bounds__(512, 4) void fused_kernel(
    const float* __restrict__ x, const float* __restrict__ A,
    const float* __restrict__ Bm, const float* __restrict__ lam_p,
    const bf16_t* __restrict__ wp3, const float* __restrict__ biasmat,
    float* __restrict__ out)
{
  __shared__ __align__(16) bf16_t Bs[2 * 128 * 64];  // 32 KB dbuf, rows 128B, XOR-swz
  __shared__ __align__(16) bf16_t Xs[256 * 32];      // 16 KB [row=dt*64+ci][v] swizzled
  __shared__ __align__(16) bf16_t Ms[KNUM * 32 * 32];// 12 KB [k][w][v] swizzled, zero-pad

  const int b = blockIdx.x;
  const int n = b >> 4;                  // 0..31
  const int t0 = (b & 15) << 2;          // t-group of 4
  const int tid = threadIdx.x;
  const int wv = tid >> 6, ln = tid & 63;
  const int lw = ln & 15, lg = ln >> 4;
  const float lam = lam_p[0];

  // stage Ms once: row R=k*32+w (64B), group-XOR sw2=(w&3)^((w>>2)&3)
  for (int i = tid; i < KNUM * 32 * 32; i += 512) {
    int R = i >> 5, v = i & 31;
    int k = i >> 10, w = (i >> 5) & 31;
    float val = 0.f;
    if (w < VV && v < VV)
      val = (k < ET) ? A[(k * VV + v) * VV + w]
                     : lam * Bm[(((n * ET) + (k - ET)) * VV + v) * VV + w];
    int sw2 = (w & 3) ^ ((w >> 2) & 3);
    int byteoff = R * 64 + ((((v >> 3) ^ sw2) & 3) << 4) + ((v & 7) << 1);
    *(bf16_t*)((char*)Ms + byteoff) = (bf16_t)val;
  }

  f32x4 acc[4][4] = {};
  const int m_base = (wv >> 1) * 64;
  const int mb4 = (wv >> 1) * 4;         // mi base for A-fragments
  const int n_base = (wv & 1) * 64;
  const f32x4 z4 = {0.f, 0.f, 0.f, 0.f};
  const int msw2 = (lw & 3) ^ ((lw >> 2) & 3);   // Ms read swizzle

  #pragma unroll 1
  for (int cb = 0; cb < 4; ++cb) {
    __syncthreads();   // all waves done reading previous cb's Xs
    // stage Xs (R7 verbatim): rows dt*64+ci, group-XOR swizzle
    if (tid < 256) {
      int ci = tid >> 2, dt = tid & 3;
      const float* xp = x + ((long)(n * CIN + cb * 64 + ci) * TDIM + t0 + dt) * VV;
      float xv[25];
      #pragma unroll
      for (int v = 0; v < VV; ++v) xv[v] = xp[v];
      int row = dt * 64 + ci;
      int sw = (row & 3) ^ ((row >> 2) & 3);
      #pragma unroll
      for (int g = 0; g < 4; ++g) {
        char* base = (char*)Xs + row * 64 + ((g ^ sw) & 3) * 16;
        #pragma unroll
        for (int p = 0; p < 4; ++p) {
          int v0 = g * 8 + p * 2;
          float lo = (v0     < VV) ? xv[v0 < VV ? v0 : 0]     : 0.f;
          float hi = (v0 + 1 < VV) ? xv[v0 + 1 < VV ? v0 + 1 : 0] : 0.f;
          *(unsigned*)(base + p * 4) = packbf(lo, hi);
        }
      }
    }
    __syncthreads();   // Xs visible

    #pragma unroll 1
    for (int k = 0; k < KNUM; ++k) {
      const int s = cb * 6 + k;
      const int buf = (s & 1) * (128 * 64);
      const bf16_t* wpS = wp3 + (((long)s * 2048 + (long)mb4 * 128 + ln) << 3);

      // A fragments kk=0 only (peak liveness 16 VGPR; hidden under #1)
      bf16x8 af2a[4];
      #pragma unroll
      for (int i = 0; i < 4; ++i)
        af2a[i] = *(const bf16x8*)(wpS + ((i * 128) << 3));

      // MFMA#1: Xs x Ms -> Bs[buf]
      bf16x8 mb0 = *(const bf16x8*)((const char*)Ms + (k * 32 + lw) * 64 + (((lg ^ msw2) & 3) << 4));
      bf16x8 mb1 = *(const bf16x8*)((const char*)Ms + (k * 32 + 16 + lw) * 64 + (((lg ^ msw2) & 3) << 4));
      #pragma unroll
      for (int rt = 0; rt < 2; ++rt) {
        int arow = wv * 32 + rt * 16 + lw;
        int sw = (arow & 3) ^ ((arow >> 2) & 3);
        int off = ((lg ^ sw) & 3) << 4;
        bf16x8 af = *(const bf16x8*)((const char*)Xs + arow * 64 + off);
        f32x4 d0 = __builtin_amdgcn_mfma_f32_16x16x32_bf16(af, mb0, z4, 0, 0, 0);
        f32x4 d1 = __builtin_amdgcn_mfma_f32_16x16x32_bf16(af, mb1, z4, 0, 0, 0);
        int rbase = wv * 32 + rt * 16 + (lg << 2);
        int dt = rbase >> 6, ci0 = rbase & 63;
        int r0 = dt * 32 + lw;
        int g0 = ((ci0 >> 3) ^ (r0 & 7)) & 7;
        char* c0 = (char*)(Bs + buf) + r0 * 128 + (g0 << 4) + ((ci0 << 1) & 15);
        *(unsigned*)(c0)     = packbf(d0[0], d0[1]);
        *(unsigned*)(c0 + 4) = packbf(d0[2], d0[3]);
        char* c1 = (char*)(Bs + buf) + (r0 + 16) * 128 + (g0 << 4) + ((ci0 << 1) & 15);
        *(unsigned*)(c1)     = packbf(d1[0], d1[1]);
        *(unsigned*)(c1 + 4) = packbf(d1[2], d1[3]);
      }
      __syncthreads();   // Bs[buf] ready (single barrier per step; dbuf)

      // MFMA#2 kk=0 (prefetched A-frags)
      __builtin_amdgcn_s_setprio(1);
      {
        bf16x8 bf2[4];
        #pragma unroll
        for (int j = 0; j < 4; ++j) {
          int rr = n_base + j * 16 + lw;
          int gg = (lg ^ (rr & 7)) & 7;
          bf2[j] = *(const bf16x8*)((const char*)(Bs + buf) + rr * 128 + (gg << 4));
        }
        #pragma unroll
        for (int i = 0; i < 4; ++i)
          #pragma unroll
          for (int j = 0; j < 4; ++j)
            acc[i][j] = __builtin_amdgcn_mfma_f32_16x16x32_bf16(af2a[i], bf2[j], acc[i][j], 0, 0, 0);
      }
      // MFMA#2 kk=1 (A-frags loaded at use; TLP covers the L2 latency)
      {
        bf16x8 af2b[4];
        #pragma unroll
        for (int i = 0; i < 4; ++i)
          af2b[i] = *(const bf16x8*)(wpS + ((i * 128 + 64) << 3));
        bf16x8 bf2[4];
        #pragma unroll
        for (int j = 0; j < 4; ++j) {
          int rr = n_base + j * 16 + lw;
          int gg = ((4 + lg) ^ (rr & 7)) & 7;
          bf2[j] = *(const bf16x8*)((const char*)(Bs + buf) + rr * 128 + (gg << 4));
        }
        #pragma unroll
        for (int i = 0; i < 4; ++i)
          #pragma unroll
          for (int j = 0; j < 4; ++j)
            acc[i][j] = __builtin_amdgcn_mfma_f32_16x16x32_bf16(af2b[i], bf2[j], acc[i][j], 0, 0, 0);
      }
      __builtin_amdgcn_s_setprio(0);
      __syncthreads();   // all waves done reading Bs[buf] before next overwrite
    }
  }

  // epilogue: C/D map col=lane&15, row=(lane>>4)*4+reg [m89-verified]
  #pragma unroll
  for (int j = 0; j < 4; ++j) {
    int colb = n_base + j * 16 + lw;         // 0..127
    int dt = colb >> 5, w = colb & 31;
    if (w < VV) {
      float* ob = out + (long)n * 409600 + (t0 + dt) * 25 + w;
      const float* brow = biasmat + (n * 25 + w) * 256;
      #pragma unroll
      for (int i = 0; i < 4; ++i) {
        int mb = m_base + i * 16 + (lg << 2);
        #pragma unroll
        for (int r = 0; r < 4; ++r) {
          int m = mb + r;
          ob[(long)m * 1600] = acc[i][j][r] + brow[m];
        }
      }
    }
  }
}

// ---------------- ws-free fp32 fallback (insurance) ----------------
__global__ __launch_bounds__(256) void fallback_kernel(
    const float* __restrict__ x, const float* __restrict__ A,
    const float* __restrict__ Bm, const float* __restrict__ lam_p,
    const float* __restrict__ W, const float* __restrict__ bvec,
    float* __restrict__ out)
{
  __shared__ __align__(16) float xs[CIN][28];
  __shared__ __align__(16) float Ms[KNUM][VV][28];   // [k][v][w] padded
  const int nt = blockIdx.x;
  const int n = nt >> 6, t = nt & 63;
  const int tid = threadIdx.x;
  const float lam = lam_p[0];

  const float* xp = x + (((long)(n * CIN + tid) * TDIM + t) * VV);
  #pragma unroll
  for (int v = 0; v < VV; ++v) xs[tid][v] = xp[v];
  xs[tid][25] = xs[tid][26] = xs[tid][27] = 0.f;
  for (int i = tid; i < KNUM * VV * VV; i += 256) {
    int k = i / (VV * VV);
    int r = i - k * VV * VV;
    int v = r / VV;
    int w = r - v * VV;
    Ms[k][v][w] = (k < ET) ? A[(k * VV + v) * VV + w]
                           : lam * Bm[(((n * ET) + (k - ET)) * VV + v) * VV + w];
    if (w == 24) { Ms[k][v][25] = Ms[k][v][26] = Ms[k][v][27] = 0.f; }
  }
  __syncthreads();

  float oacc[28] = {};
  for (int k = 0; k < KNUM; ++k) {
    float yv[28];
    float bv = bvec[(k << 8) + tid];
    #pragma unroll
    for (int v = 0; v < 28; ++v) yv[v] = 0.f;
    for (int ci = 0; ci < CIN; ++ci) {
      float wl = W[ci * KD + (k << 8) + tid];
      const f32x4* x4 = (const f32x4*)&xs[ci][0];
      #pragma unroll
      for (int q = 0; q < 7; ++q) {
        f32x4 xv = x4[q];
        yv[q*4+0] += wl*xv[0]; yv[q*4+1] += wl*xv[1];
        yv[q*4+2] += wl*xv[2]; yv[q*4+3] += wl*xv[3];
      }
    }
    #pragma unroll
    for (int v = 0; v < VV; ++v) {
      float yvv = yv[v] + bv;
      const f32x4* m4 = (const f32x4*)&Ms[k][v][0];
      #pragma unroll
      for (int q = 0; q < 7; ++q) {
        f32x4 mv = m4[q];
        oacc[q*4+0] += yvv*mv[0]; oacc[q*4+1] += yvv*mv[1];
        oacc[q*4+2] += yvv*mv[2]; oacc[q*4+3] += yvv*mv[3];
      }
    }
  }
  float* op = out + (((long)(n * COUT + tid) * TDIM + t) * VV);
  #pragma unroll
  for (int w = 0; w < VV; ++w) op[w] = oacc[w];
}

__global__ void copyA_kernel(const float* __restrict__ A, float* __restrict__ outA) {
  int i = blockIdx.x * 256 + threadIdx.x;
  if (i < ACNT) outA[i] = A[i];
}

extern "C" void kernel_launch(void* const* d_in, const int* in_sizes, int n_in,
                              void* d_out, int out_size, void* d_ws, size_t ws_size,
                              hipStream_t stream) {
  const float* x   = (const float*)d_in[0];
  const float* A   = (const float*)d_in[1];
  const float* Bm  = (const float*)d_in[2];
  const float* lam = (const float*)d_in[3];
  const float* W   = (const float*)d_in[4];
  const float* bv  = (const float*)d_in[5];
  float* out = (float*)d_out;

  if (d_ws != nullptr && ws_size >= WS_NEED) {
    bf16_t* wp3     = (bf16_t*)d_ws;
    float*  biasmat = (float*)((char*)d_ws + BIAS_OFF);
    constexpr int PREP_ITEMS = WP3_CHUNKS + NB * VV * COUT + ACNT;
    prep_kernel<<<(PREP_ITEMS + 255) / 256, 256, 0, stream>>>(A, Bm, lam, W, bv, wp3, biasmat, out + OUT0);
    fused_kernel<<<NB * 16, 512, 0, stream>>>(x, A, Bm, lam, wp3, biasmat, out);
  } else {
    fallback_kernel<<<NB * TDIM, 256, 0, stream>>>(x, A, Bm, lam, W, bv, out);
    copyA_kernel<<<(ACNT + 255) / 256, 256, 0, stream>>>(A, out + OUT0);
  }
}